// Round 7
// baseline (285.549 us; speedup 1.0000x reference)
//
#include <hip/hip_runtime.h>
#include <cstddef>
#include <cstdint>

// ---------------------------------------------------------------------------
// AFNO: rfft2(32x32, ortho) -> block-diag complex 2-layer MLP -> irfft2
// Round 7: k2 compacted to 3 LDS regions (38 KB -> 4 WG/CU) + reverted to
// 4 weight mats with neg8 on A-frags (weight L2 stream 2.25 -> 1.92 GB).
// ---------------------------------------------------------------------------

typedef __attribute__((ext_vector_type(8))) short bf16x8;
typedef __attribute__((ext_vector_type(4))) float f32x4;

namespace {

constexpr int BATCH = 64;
constexpr int WF    = 17;   // 32/2 + 1
constexpr int CC    = 768;
constexpr int BLK   = 192;

// 16 weight mats (W1r,W1i,W2r,W2i x 4blk), 8 twiddle mats
constexpr size_t W_ELEMS  = 16u * 36864u;          // 589824
constexpr size_t TW_ELEMS = 8u * 1024u;            // 8192
constexpr size_t PW_ELEMS = W_ELEMS + TW_ELEMS;    // 598016

// spectrum: [b][kw][plane(2)][csubg(48)][512] ushorts
// within a 512-chunk: pos = hp*32 + ((c&15) ^ ((hp&7)<<1))*2 + (h&1)
constexpr int PLANE_U = 48 * 512;                  // 24576 ushorts

constexpr float C32[32] = {
   1.0000000000f,  0.9807852804f,  0.9238795325f,  0.8314696123f,
   0.7071067812f,  0.5555702330f,  0.3826834324f,  0.1950903220f,
   0.0000000000f, -0.1950903220f, -0.3826834324f, -0.5555702330f,
  -0.7071067812f, -0.8314696123f, -0.9238795325f, -0.9807852804f,
  -1.0000000000f, -0.9807852804f, -0.9238795325f, -0.8314696123f,
  -0.7071067812f, -0.5555702330f, -0.3826834324f, -0.1950903220f,
   0.0000000000f,  0.1950903220f,  0.3826834324f,  0.5555702330f,
   0.7071067812f,  0.8314696123f,  0.9238795325f,  0.9807852804f
};
constexpr float S32[32] = {
   0.0000000000f,  0.1950903220f,  0.3826834324f,  0.5555702330f,
   0.7071067812f,  0.8314696123f,  0.9238795325f,  0.9807852804f,
   1.0000000000f,  0.9807852804f,  0.9238795325f,  0.8314696123f,
   0.7071067812f,  0.5555702330f,  0.3826834324f,  0.1950903220f,
   0.0000000000f, -0.1950903220f, -0.3826834324f, -0.5555702330f,
  -0.7071067812f, -0.8314696123f, -0.9238795325f, -0.9807852804f,
  -1.0000000000f, -0.9807852804f, -0.9238795325f, -0.8314696123f,
  -0.7071067812f, -0.5555702330f, -0.3826834324f, -0.1950903220f
};

} // namespace

__device__ __forceinline__ ushort f2bf(float f) {
    union { float f; unsigned u; } v; v.f = f;
    const unsigned r = (v.u + 0x7FFFu + ((v.u >> 16) & 1u)) >> 16;
    return (ushort)r;
}
// pack two f32 -> (bf16 lo, bf16 hi) u32 — pure C (proven; NO inline asm)
__device__ __forceinline__ uint pk(float lo, float hi) {
    return (uint)f2bf(lo) | ((uint)f2bf(hi) << 16);
}
__device__ __forceinline__ bf16x8 neg8(bf16x8 a) {
    union { bf16x8 v; uint4 u; } t; t.v = a;
    t.u.x ^= 0x80008000u; t.u.y ^= 0x80008000u;
    t.u.z ^= 0x80008000u; t.u.w ^= 0x80008000u;
    return t.v;
}

// ---------------------------------------------------------------------------
// Pre-pack.
// Weights (B-frag layout): pw[(mat*4+blk)][kk][nf][lane][i],
//   d = kk*32+(lane>>4)*8+i, col = nf*16+(lane&15)
//   mat: 0 W1r, 1 W1i, 2 W2r, 3 W2i
// Twiddles (A-frag layout): TW[mat][mf][lane][i], row = mf*16+(lane&15),
//   col = (lane>>4)*8+i
//   mat: 0 C/32, 1 S/32, 2 -S/32, 3 C, 4 S, 5 -S,
//        6 A_ir (irfft cos-side /32, cols>16 zero), 7 B_ir (sin-side)
// ---------------------------------------------------------------------------
__global__ __launch_bounds__(256) void k_pack(const float* __restrict__ w1,
                                              const float* __restrict__ w2,
                                              ushort* __restrict__ pw) {
    const unsigned idx = blockIdx.x * 256u + threadIdx.x;
    if (idx < W_ELEMS) {
        const unsigned mi = idx / 36864u;       // mat*4 + blk
        const unsigned r  = idx % 36864u;
        const unsigned kk = r / 6144u;
        const unsigned r2 = r % 6144u;
        const unsigned nf = r2 / 512u;
        const unsigned r3 = r2 % 512u;
        const unsigned lane = r3 / 8u;
        const unsigned i  = r3 % 8u;
        const unsigned d   = kk * 32u + (lane >> 4) * 8u + i;
        const unsigned col = nf * 16u + (lane & 15u);
        const unsigned mat = mi >> 2, blk = mi & 3u;
        const float* src;
        if      (mat == 0u) src = w1 + (size_t)(0 * 4 + blk) * BLK * BLK;
        else if (mat == 1u) src = w1 + (size_t)(1 * 4 + blk) * BLK * BLK;
        else if (mat == 2u) src = w2 + (size_t)(0 * 4 + blk) * BLK * BLK;
        else                src = w2 + (size_t)(1 * 4 + blk) * BLK * BLK;
        pw[idx] = f2bf(src[(size_t)d * BLK + col]);
    } else if (idx < PW_ELEMS) {
        const unsigned t = idx - (unsigned)W_ELEMS;   // 0..8191
        const unsigned mat = t >> 10;
        const unsigned rr  = t & 1023u;
        const unsigned mf  = rr >> 9;
        const unsigned q   = rr & 511u;
        const unsigned lane = q >> 3, i = q & 7u;
        const unsigned row = mf * 16u + (lane & 15u);   // output idx (kh / w)
        const unsigned col = (lane >> 4) * 8u + i;      // reduce idx (h / kw)
        const unsigned ang = (row * col) & 31u;
        float v;
        if      (mat == 0u) v = C32[ang] * 0.03125f;
        else if (mat == 1u) v = S32[ang] * 0.03125f;
        else if (mat == 2u) v = -S32[ang] * 0.03125f;
        else if (mat == 3u) v = C32[ang];
        else if (mat == 4u) v = S32[ang];
        else if (mat == 5u) v = -S32[ang];
        else if (mat == 6u) {
            if      (col == 0u)  v = 0.03125f;
            else if (col < 16u)  v = 2.f * C32[ang] * 0.03125f;
            else if (col == 16u) v = C32[(16u * row) & 31u] * 0.03125f;
            else                 v = 0.f;
        } else {
            v = (col >= 1u && col <= 15u) ? (-2.f * S32[ang] * 0.03125f) : 0.f;
        }
        pw[idx] = f2bf(v);
    }
}

// ---------------------------------------------------------------------------
// k1: W-FFT as MFMA.  WG = (b, hp, cq=192c).  Yr = C*X, Yi = -S*X (unscaled).
// LDS: X as w-pair u32s [16wp][384col] (col = c + 192*hLocal), col XOR lg<<3.
// Stores kw 0..16 as h-pair u32s into the spectrum layout.
// ---------------------------------------------------------------------------
__global__ __launch_bounds__(256) void k_rfft_w(const float* __restrict__ x,
                                                ushort* __restrict__ spec,
                                                const ushort* __restrict__ pw) {
    __shared__ uint xb[16 * 384];

    const int bid = blockIdx.x;
    const int cq = bid & 3;
    const int hp = (bid >> 2) & 15;
    const int b  = bid >> 6;
    const int tid = threadIdx.x;
    const int wv = tid >> 6, l = tid & 63, lc = l & 15, lg = l >> 4;

    // ---- stage x -> LDS (bf16 w-pair u32s) ----
#pragma unroll
    for (int it = 0; it < 6; ++it) {
        const int flat = it * 256 + tid;        // 0..1535
        const int h  = flat / 768;
        const int rm = flat % 768;
        const int wp = rm / 48;
        const int c4 = rm % 48;
        const float* p = x + ((size_t)(b * 1024 + (hp * 2 + h) * 32 + wp * 2) * CC)
                           + cq * 192 + c4 * 4;
        const float4 a  = *(const float4*)p;
        const float4 bb = *(const float4*)(p + CC);
        uint4 u;
        u.x = pk(a.x, bb.x); u.y = pk(a.y, bb.y);
        u.z = pk(a.z, bb.z); u.w = pk(a.w, bb.w);
        const int col = (h * 192 + c4 * 4) ^ (((wp >> 2) & 3) << 3);
        *(uint4*)&xb[wp * 384 + col] = u;
    }
    __syncthreads();

    const ushort* TW = pw + W_ELEMS;
    bf16x8 ac[2], as[2];
#pragma unroll
    for (int m = 0; m < 2; ++m) {
        ac[m] = *(const bf16x8*)(TW + ((size_t)(3 * 2 + m) * 64 + l) * 8);  // C
        as[m] = *(const bf16x8*)(TW + ((size_t)(5 * 2 + m) * 64 + l) * 8);  // -S
    }

    f32x4 aR[2][6] = {}, aI[2][6] = {};
#pragma unroll
    for (int j = 0; j < 6; ++j) {
        const int nf = (j < 3) ? (wv * 3 + j) : (12 + wv * 3 + (j - 3));
        union { bf16x8 v; uint d[4]; } u;
#pragma unroll
        for (int t = 0; t < 4; ++t) {
            const int wp = lg * 4 + t;
            u.d[t] = xb[wp * 384 + ((nf * 16 + lc) ^ (lg << 3))];
        }
#pragma unroll
        for (int m = 0; m < 2; ++m) {
            aR[m][j] = __builtin_amdgcn_mfma_f32_16x16x32_bf16(ac[m], u.v, aR[m][j], 0, 0, 0);
            aI[m][j] = __builtin_amdgcn_mfma_f32_16x16x32_bf16(as[m], u.v, aI[m][j], 0, 0, 0);
        }
    }

    // ---- store kw<=16 as (h0,h1) u32 pairs ----
    uint* spec32 = (uint*)spec;
    const int swz = (hp & 7) << 1;
#pragma unroll
    for (int m = 0; m < 2; ++m)
#pragma unroll
        for (int j = 0; j < 3; ++j)
#pragma unroll
            for (int r = 0; r < 4; ++r) {
                if (m == 1 && (lg != 0 || r != 0)) continue;   // keep kw==16 only
                const int kw = m * 16 + lg * 4 + r;
                const int csub = cq * 12 + wv * 3 + j;
                const size_t pos = ((size_t)(b * WF + kw) * 2) * 12288
                                 + csub * 256 + hp * 16 + (lc ^ swz);
                spec32[pos]         = pk(aR[m][j][r], aR[m][j + 3][r]);
                spec32[pos + 12288] = pk(aI[m][j][r], aI[m][j + 3][r]);
            }
}

// ---------------------------------------------------------------------------
// k2: fused fftH + S1 + S2 + S3 + ifftH, per (blk, b, kw) tile.
// THREE LDS regions (12 csub x 528 ushorts each), 38 KB -> 4 WG/CU:
//  R0: Xilv -> Ysub(r) -> r1sub -> r2sub
//  R1: Xilv(i) -> Ysub(i) -> i1sub -> i2_t(ilv)
//  R2: r2_t(ilv)
// 7 barriers: A load, B P1-stores, C P2-reads, D P2-stores, E P3-reads,
//             F P3-stores, G P4-reads (before i2_t overwrites i1).
// ---------------------------------------------------------------------------
__global__ __launch_bounds__(256, 4) void k_fft_mix(
        ushort* __restrict__ spec,
        const ushort* __restrict__ pw,
        const float* __restrict__ b1, const float* __restrict__ b2) {

    __shared__ ushort lds[3][6336];

    const int bid = blockIdx.x;
    const int blk = bid / (BATCH * WF);
    const int rem = bid % (BATCH * WF);
    const int b   = rem / WF;
    const int kw  = rem % WF;
    const int tid = threadIdx.x;
    const int wv = tid >> 6, l = tid & 63, lc = l & 15, lg = l >> 4;

    const size_t gR = ((size_t)(b * WF + kw) * 2) * PLANE_U + blk * 6144;
    const size_t gI = gR + PLANE_U;

#pragma unroll
    for (int j = 0; j < 3; ++j) {
        const int q = tid + 256 * j;
        const int dst = (q >> 6) * 528 + (q & 63) * 8;
        *(uint4*)&lds[0][dst] = *(const uint4*)(spec + gR + q * 8);
        *(uint4*)&lds[1][dst] = *(const uint4*)(spec + gI + q * 8);
    }
    __syncthreads();                                   // A

    const ushort* TW = pw + W_ELEMS;
    const int col0 = wv * 48;

    // ================= P1: forward H-FFT (in-place own stripes) ====
    {
        bf16x8 xr[3], xi[3];
#pragma unroll
        for (int n = 0; n < 3; ++n) {
            const int csub = wv * 3 + n;
            union { bf16x8 v; uint d[4]; } ur, ui;
#pragma unroll
            for (int t = 0; t < 4; ++t) {
                const int hp = lg * 4 + t;
                const int pos = csub * 528 + hp * 32 + ((lc ^ ((hp & 7) << 1)) << 1);
                ur.d[t] = *(const uint*)&lds[0][pos];
                ui.d[t] = *(const uint*)&lds[1][pos];
            }
            xr[n] = ur.v; xi[n] = ui.v;
        }
        bf16x8 cf[2], sf[2], sfn[2];
#pragma unroll
        for (int m = 0; m < 2; ++m) {
            cf[m]  = *(const bf16x8*)(TW + ((size_t)(0 * 2 + m) * 64 + l) * 8);
            sf[m]  = *(const bf16x8*)(TW + ((size_t)(1 * 2 + m) * 64 + l) * 8);
            sfn[m] = *(const bf16x8*)(TW + ((size_t)(2 * 2 + m) * 64 + l) * 8);
        }
        f32x4 yr[2][3] = {}, yi[2][3] = {};
#pragma unroll
        for (int m = 0; m < 2; ++m)
#pragma unroll
            for (int n = 0; n < 3; ++n) {
                yr[m][n] = __builtin_amdgcn_mfma_f32_16x16x32_bf16(cf[m],  xr[n], yr[m][n], 0, 0, 0);
                yr[m][n] = __builtin_amdgcn_mfma_f32_16x16x32_bf16(sf[m],  xi[n], yr[m][n], 0, 0, 0);
                yi[m][n] = __builtin_amdgcn_mfma_f32_16x16x32_bf16(cf[m],  xi[n], yi[m][n], 0, 0, 0);
                yi[m][n] = __builtin_amdgcn_mfma_f32_16x16x32_bf16(sfn[m], xr[n], yi[m][n], 0, 0, 0);
            }
#pragma unroll
        for (int m = 0; m < 2; ++m)
#pragma unroll
            for (int n = 0; n < 3; ++n)
#pragma unroll
                for (int rp = 0; rp < 2; ++rp) {
                    const uint ur = pk(yr[m][n][2 * rp], yr[m][n][2 * rp + 1]);
                    const uint ui = pk(yi[m][n][2 * rp], yi[m][n][2 * rp + 1]);
                    const int p0 = (wv * 3 + n) * 528 + (m * 16 + lg * 4 + 2 * rp) * 16 + lc;
                    lds[0][p0] = (ushort)ur; lds[0][p0 + 16] = (ushort)(ur >> 16);
                    lds[1][p0] = (ushort)ui; lds[1][p0 + 16] = (ushort)(ui >> 16);
                }
    }
    __syncthreads();                                   // B

    const ushort* pW1r = pw + (size_t)(0 * 4 + blk) * 36864;
    const ushort* pW1i = pw + (size_t)(1 * 4 + blk) * 36864;
    const ushort* pW2r = pw + (size_t)(2 * 4 + blk) * 36864;
    const ushort* pW2i = pw + (size_t)(3 * 4 + blk) * 36864;

    // ================= P2: layer 1 + relu =================
    {
        f32x4 aR[2][3], aI[2][3];
#pragma unroll
        for (int n = 0; n < 3; ++n) {
            const float br = b1[(size_t)(0 * 4 + blk) * BLK + col0 + n * 16 + lc];
            const float bi = b1[(size_t)(1 * 4 + blk) * BLK + col0 + n * 16 + lc];
#pragma unroll
            for (int m = 0; m < 2; ++m) {
                aR[m][n] = (f32x4){br, br, br, br};
                aI[m][n] = (f32x4){bi, bi, bi, bi};
            }
        }
#pragma unroll
        for (int kk = 0; kk < 6; ++kk) {
            const int csubA = 2 * kk + (lg >> 1);
            const int apos  = csubA * 528 + lc * 16 + (lg & 1) * 8;
            bf16x8 ar[2], ai[2], ain[2];
#pragma unroll
            for (int m = 0; m < 2; ++m) {
                ar[m]  = *(const bf16x8*)&lds[0][apos + m * 256];
                ai[m]  = *(const bf16x8*)&lds[1][apos + m * 256];
                ain[m] = neg8(ai[m]);
            }
            bf16x8 wr[3], wi[3];
#pragma unroll
            for (int n = 0; n < 3; ++n) {
                const size_t off = ((size_t)(kk * 12 + wv * 3 + n) * 64 + l) * 8;
                wr[n] = *(const bf16x8*)(pW1r + off);
                wi[n] = *(const bf16x8*)(pW1i + off);
            }
#pragma unroll
            for (int m = 0; m < 2; ++m)
#pragma unroll
                for (int n = 0; n < 3; ++n) {
                    aR[m][n] = __builtin_amdgcn_mfma_f32_16x16x32_bf16(ar[m],  wr[n], aR[m][n], 0, 0, 0);
                    aR[m][n] = __builtin_amdgcn_mfma_f32_16x16x32_bf16(ain[m], wi[n], aR[m][n], 0, 0, 0);
                    aI[m][n] = __builtin_amdgcn_mfma_f32_16x16x32_bf16(ar[m],  wi[n], aI[m][n], 0, 0, 0);
                    aI[m][n] = __builtin_amdgcn_mfma_f32_16x16x32_bf16(ai[m],  wr[n], aI[m][n], 0, 0, 0);
                }
        }
        __syncthreads();                               // C (all Y reads done)
#pragma unroll
        for (int m = 0; m < 2; ++m)
#pragma unroll
            for (int n = 0; n < 3; ++n)
#pragma unroll
                for (int rp = 0; rp < 2; ++rp) {
                    const uint ur = pk(fmaxf(aR[m][n][2 * rp], 0.f), fmaxf(aR[m][n][2 * rp + 1], 0.f));
                    const uint ui = pk(fmaxf(aI[m][n][2 * rp], 0.f), fmaxf(aI[m][n][2 * rp + 1], 0.f));
                    const int p0 = (wv * 3 + n) * 528 + (m * 16 + lg * 4 + 2 * rp) * 16 + lc;
                    lds[0][p0] = (ushort)ur; lds[0][p0 + 16] = (ushort)(ur >> 16);
                    lds[1][p0] = (ushort)ui; lds[1][p0 + 16] = (ushort)(ui >> 16);
                }
    }
    __syncthreads();                                   // D

    // ================= P3: r2 = r1 W2r - i1 W2i + b2r =================
    {
        f32x4 cR[2][3];
#pragma unroll
        for (int n = 0; n < 3; ++n) {
            const float br = b2[(size_t)(0 * 4 + blk) * BLK + col0 + n * 16 + lc];
#pragma unroll
            for (int m = 0; m < 2; ++m) cR[m][n] = (f32x4){br, br, br, br};
        }
#pragma unroll
        for (int kk = 0; kk < 6; ++kk) {
            const int csubA = 2 * kk + (lg >> 1);
            const int apos  = csubA * 528 + lc * 16 + (lg & 1) * 8;
            bf16x8 ar[2], ain[2];
#pragma unroll
            for (int m = 0; m < 2; ++m) {
                ar[m]  = *(const bf16x8*)&lds[0][apos + m * 256];
                ain[m] = neg8(*(const bf16x8*)&lds[1][apos + m * 256]);
            }
            bf16x8 wr[3], wi[3];
#pragma unroll
            for (int n = 0; n < 3; ++n) {
                const size_t off = ((size_t)(kk * 12 + wv * 3 + n) * 64 + l) * 8;
                wr[n] = *(const bf16x8*)(pW2r + off);
                wi[n] = *(const bf16x8*)(pW2i + off);
            }
#pragma unroll
            for (int m = 0; m < 2; ++m)
#pragma unroll
                for (int n = 0; n < 3; ++n) {
                    cR[m][n] = __builtin_amdgcn_mfma_f32_16x16x32_bf16(ar[m],  wr[n], cR[m][n], 0, 0, 0);
                    cR[m][n] = __builtin_amdgcn_mfma_f32_16x16x32_bf16(ain[m], wi[n], cR[m][n], 0, 0, 0);
                }
        }
        __syncthreads();                               // E (all r1/i1 reads done)
#pragma unroll
        for (int m = 0; m < 2; ++m)
#pragma unroll
            for (int n = 0; n < 3; ++n) {
                const int csub = wv * 3 + n;
#pragma unroll
                for (int rp = 0; rp < 2; ++rp) {
                    const uint p = pk(cR[m][n][2 * rp], cR[m][n][2 * rp + 1]);
                    const int kh0 = m * 16 + lg * 4 + 2 * rp;
                    lds[0][csub * 528 + kh0 * 16 + lc]       = (ushort)p;
                    lds[0][csub * 528 + (kh0 + 1) * 16 + lc] = (ushort)(p >> 16);
                    const int hp = kh0 >> 1;
                    const int post = csub * 528 + hp * 32 + ((lc ^ ((hp & 7) << 1)) << 1);
                    *(uint*)&lds[2][post] = p;
                }
            }
    }
    __syncthreads();                                   // F

    // ================= P4: i2 = r2 W2i + i1 W2r + b2i =================
    {
        f32x4 cI[2][3];
#pragma unroll
        for (int n = 0; n < 3; ++n) {
            const float bi = b2[(size_t)(1 * 4 + blk) * BLK + col0 + n * 16 + lc];
#pragma unroll
            for (int m = 0; m < 2; ++m) cI[m][n] = (f32x4){bi, bi, bi, bi};
        }
#pragma unroll
        for (int kk = 0; kk < 6; ++kk) {
            const int csubA = 2 * kk + (lg >> 1);
            const int apos  = csubA * 528 + lc * 16 + (lg & 1) * 8;
            bf16x8 a2[2], i1[2];
#pragma unroll
            for (int m = 0; m < 2; ++m) {
                a2[m] = *(const bf16x8*)&lds[0][apos + m * 256];   // r2
                i1[m] = *(const bf16x8*)&lds[1][apos + m * 256];   // i1
            }
            bf16x8 wi[3], wr[3];
#pragma unroll
            for (int n = 0; n < 3; ++n) {
                const size_t off = ((size_t)(kk * 12 + wv * 3 + n) * 64 + l) * 8;
                wi[n] = *(const bf16x8*)(pW2i + off);
                wr[n] = *(const bf16x8*)(pW2r + off);
            }
#pragma unroll
            for (int m = 0; m < 2; ++m)
#pragma unroll
                for (int n = 0; n < 3; ++n) {
                    cI[m][n] = __builtin_amdgcn_mfma_f32_16x16x32_bf16(a2[m], wi[n], cI[m][n], 0, 0, 0);
                    cI[m][n] = __builtin_amdgcn_mfma_f32_16x16x32_bf16(i1[m], wr[n], cI[m][n], 0, 0, 0);
                }
        }
        __syncthreads();                               // G (all i1 reads done)
        // i2_t -> R1 (own stripes; consumed only by this wave in P5)
#pragma unroll
        for (int m = 0; m < 2; ++m)
#pragma unroll
            for (int n = 0; n < 3; ++n) {
                const int csub = wv * 3 + n;
#pragma unroll
                for (int rp = 0; rp < 2; ++rp) {
                    const int hp = (m * 16 + lg * 4 + 2 * rp) >> 1;
                    const int post = csub * 528 + hp * 32 + ((lc ^ ((hp & 7) << 1)) << 1);
                    *(uint*)&lds[1][post] = pk(cI[m][n][2 * rp], cI[m][n][2 * rp + 1]);
                }
            }
    }
    // no barrier: P5 reads only this wave's own stripes

    // ================= P5: inverse H-FFT + store =================
    {
        bf16x8 ci[2], si[2], sn[2];
#pragma unroll
        for (int m = 0; m < 2; ++m) {
            ci[m] = *(const bf16x8*)(TW + ((size_t)(3 * 2 + m) * 64 + l) * 8);
            si[m] = *(const bf16x8*)(TW + ((size_t)(4 * 2 + m) * 64 + l) * 8);
            sn[m] = *(const bf16x8*)(TW + ((size_t)(5 * 2 + m) * 64 + l) * 8);
        }
        bf16x8 r2b[3], i2b[3];
#pragma unroll
        for (int n = 0; n < 3; ++n) {
            const int csub = wv * 3 + n;
            union { bf16x8 v; uint d[4]; } ur, ui;
#pragma unroll
            for (int t = 0; t < 4; ++t) {
                const int hp = lg * 4 + t;
                const int pos = csub * 528 + hp * 32 + ((lc ^ ((hp & 7) << 1)) << 1);
                ur.d[t] = *(const uint*)&lds[2][pos];
                ui.d[t] = *(const uint*)&lds[1][pos];
            }
            r2b[n] = ur.v; i2b[n] = ui.v;
        }
        f32x4 zr[2][3] = {}, zi[2][3] = {};
#pragma unroll
        for (int m = 0; m < 2; ++m)
#pragma unroll
            for (int n = 0; n < 3; ++n) {
                zr[m][n] = __builtin_amdgcn_mfma_f32_16x16x32_bf16(ci[m], r2b[n], zr[m][n], 0, 0, 0);
                zr[m][n] = __builtin_amdgcn_mfma_f32_16x16x32_bf16(sn[m], i2b[n], zr[m][n], 0, 0, 0);
                zi[m][n] = __builtin_amdgcn_mfma_f32_16x16x32_bf16(ci[m], i2b[n], zi[m][n], 0, 0, 0);
                zi[m][n] = __builtin_amdgcn_mfma_f32_16x16x32_bf16(si[m], r2b[n], zi[m][n], 0, 0, 0);
            }
#pragma unroll
        for (int m = 0; m < 2; ++m)
#pragma unroll
            for (int n = 0; n < 3; ++n) {
                const size_t cbase = gR + (size_t)(wv * 3 + n) * 512;
#pragma unroll
                for (int rp = 0; rp < 2; ++rp) {
                    const int hp = (m * 16 + lg * 4 + 2 * rp) >> 1;
                    const size_t pos = cbase + hp * 32 + ((lc ^ ((hp & 7) << 1)) << 1);
                    *(uint*)(spec + pos)           = pk(zr[m][n][2 * rp], zr[m][n][2 * rp + 1]);
                    *(uint*)(spec + pos + PLANE_U) = pk(zi[m][n][2 * rp], zi[m][n][2 * rp + 1]);
                }
            }
    }
}

// ---------------------------------------------------------------------------
// k3: W-irfft as MFMA.  WG = (b, hp, cq=192c).  out = A_ir*Zr + B_ir*Zi,
// twiddle cols k>16 are zero so only raw rows 0..16 are staged (clamp reads).
// ---------------------------------------------------------------------------
__global__ __launch_bounds__(256) void k_irfft_w(const ushort* __restrict__ spec,
                                                 float* __restrict__ out,
                                                 const ushort* __restrict__ pw) {
    __shared__ uint rawR[17 * 198];
    __shared__ uint rawI[17 * 198];

    const int bid = blockIdx.x;
    const int cq = bid & 3;
    const int hp = (bid >> 2) & 15;
    const int b  = bid >> 6;
    const int tid = threadIdx.x;
    const int wv = tid >> 6, l = tid & 63, lc = l & 15, lg = l >> 4;

    const uint* spec32 = (const uint*)spec;

    // ---- stage raw 64B chunks (kw 0..16, 12 csub, 2 planes) ----
#pragma unroll
    for (int it = 0; it < 13; ++it) {
        const int slot = it * 256 + tid;
        if (slot < 3264) {
            const int part = slot & 7;            // 8B unit within chunk
            const int c2   = slot >> 3;           // 0..407
            const int plane = c2 / 204;
            const int q  = c2 % 204;
            const int kw = q / 12, csub = q % 12;
            const size_t gpos = ((size_t)(b * WF + kw) * 2 + plane) * 12288
                              + (cq * 12 + csub) * 256 + hp * 16 + part * 2;
            const uint2 v = *(const uint2*)(spec32 + gpos);
            uint* dst = plane ? rawI : rawR;
            *(uint2*)&dst[kw * 198 + csub * 16 + part * 2] = v;
        }
    }
    __syncthreads();

    const ushort* TW = pw + W_ELEMS;
    bf16x8 twA[2], twB[2];
#pragma unroll
    for (int m = 0; m < 2; ++m) {
        twA[m] = *(const bf16x8*)(TW + ((size_t)(6 * 2 + m) * 64 + l) * 8);
        twB[m] = *(const bf16x8*)(TW + ((size_t)(7 * 2 + m) * 64 + l) * 8);
    }

    int rowoff[8];
#pragma unroll
    for (int i = 0; i < 8; ++i) {
        int kwv = lg * 8 + i;
        if (kwv > 16) kwv = 16;        // clamped reads; A/B cols >16 are zero
        rowoff[i] = kwv * 396;         // ushort units
    }

    const ushort* rr = (const ushort*)rawR;
    const ushort* ri = (const ushort*)rawI;
    const int swz = (hp & 7) << 1;

    f32x4 acc[2][6] = {};
#pragma unroll
    for (int j = 0; j < 6; ++j) {
        const int coll = (wv * 6 + j) * 16 + lc;     // 0..383
        const int h  = coll & 1;
        const int cL = coll >> 1;
        const int bu = ((cL >> 4) * 16 + ((cL & 15) ^ swz)) * 2 + h;
        union { bf16x8 v; ushort s[8]; } fr, fi;
#pragma unroll
        for (int i = 0; i < 8; ++i) {
            fr.s[i] = rr[rowoff[i] + bu];
            fi.s[i] = ri[rowoff[i] + bu];
        }
#pragma unroll
        for (int m = 0; m < 2; ++m) {
            acc[m][j] = __builtin_amdgcn_mfma_f32_16x16x32_bf16(twA[m], fr.v, acc[m][j], 0, 0, 0);
            acc[m][j] = __builtin_amdgcn_mfma_f32_16x16x32_bf16(twB[m], fi.v, acc[m][j], 0, 0, 0);
        }
    }

    // ---- store fp32 output ----
#pragma unroll
    for (int m = 0; m < 2; ++m)
#pragma unroll
        for (int j = 0; j < 6; ++j) {
            const int coll = (wv * 6 + j) * 16 + lc;
            const int h  = coll & 1;
            const int c  = cq * 192 + (coll >> 1);
#pragma unroll
            for (int r = 0; r < 4; ++r) {
                const int w = m * 16 + lg * 4 + r;
                out[((size_t)(b * 1024 + (hp * 2 + h) * 32 + w)) * CC + c] = acc[m][j][r];
            }
        }
}

// ---------------------------------------------------------------------------
extern "C" void kernel_launch(void* const* d_in, const int* in_sizes, int n_in,
                              void* d_out, int out_size, void* d_ws, size_t ws_size,
                              hipStream_t stream) {
    const float* x  = (const float*)d_in[0];
    const float* w1 = (const float*)d_in[1];
    const float* b1 = (const float*)d_in[2];
    const float* w2 = (const float*)d_in[3];
    const float* b2 = (const float*)d_in[4];
    float* out = (float*)d_out;

    ushort* pw   = (ushort*)d_ws;
    ushort* spec = pw + PW_ELEMS;

    k_pack<<<dim3((unsigned)(PW_ELEMS / 256)), dim3(256), 0, stream>>>(w1, w2, pw);
    k_rfft_w<<<dim3(BATCH * 16 * 4), dim3(256), 0, stream>>>(x, spec, pw);
    k_fft_mix<<<dim3(4 * BATCH * WF), dim3(256), 0, stream>>>(spec, pw, b1, b2);
    k_irfft_w<<<dim3(BATCH * 16 * 4), dim3(256), 0, stream>>>(spec, out, pw);
}

// Round 8
// 258.507 us; speedup vs baseline: 1.1046x; 1.1046x over previous
//
#include <hip/hip_runtime.h>
#include <cstddef>
#include <cstdint>

// ---------------------------------------------------------------------------
// AFNO: rfft2(32x32, ortho) -> block-diag complex 2-layer MLP -> irfft2
// Round 8: k2 processes TWO (b,kw) tiles per WG (b-pair), weight fragments
// loaded once per kk and reused for both tiles (weight L2 traffic halved).
// 3 LDS regions per tile (76 KB dynamic LDS, 2 WG/CU). No register caps
// below 256 (r7's (256,4) caused spills -> +45MB scratch FETCH).
// ---------------------------------------------------------------------------

typedef __attribute__((ext_vector_type(8))) short bf16x8;
typedef __attribute__((ext_vector_type(4))) float f32x4;

namespace {

constexpr int BATCH = 64;
constexpr int WF    = 17;   // 32/2 + 1
constexpr int CC    = 768;
constexpr int BLK   = 192;

// 16 weight mats (W1r,W1i,W2r,W2i x 4blk), 8 twiddle mats
constexpr size_t W_ELEMS  = 16u * 36864u;          // 589824
constexpr size_t TW_ELEMS = 8u * 1024u;            // 8192
constexpr size_t PW_ELEMS = W_ELEMS + TW_ELEMS;    // 598016

// spectrum: [b][kw][plane(2)][csubg(48)][512] ushorts
// within a 512-chunk: pos = hp*32 + ((c&15) ^ ((hp&7)<<1))*2 + (h&1)
constexpr int PLANE_U = 48 * 512;                  // 24576 ushorts

constexpr float C32[32] = {
   1.0000000000f,  0.9807852804f,  0.9238795325f,  0.8314696123f,
   0.7071067812f,  0.5555702330f,  0.3826834324f,  0.1950903220f,
   0.0000000000f, -0.1950903220f, -0.3826834324f, -0.5555702330f,
  -0.7071067812f, -0.8314696123f, -0.9238795325f, -0.9807852804f,
  -1.0000000000f, -0.9807852804f, -0.9238795325f, -0.8314696123f,
  -0.7071067812f, -0.5555702330f, -0.3826834324f, -0.1950903220f,
   0.0000000000f,  0.1950903220f,  0.3826834324f,  0.5555702330f,
   0.7071067812f,  0.8314696123f,  0.9238795325f,  0.9807852804f
};
constexpr float S32[32] = {
   0.0000000000f,  0.1950903220f,  0.3826834324f,  0.5555702330f,
   0.7071067812f,  0.8314696123f,  0.9238795325f,  0.9807852804f,
   1.0000000000f,  0.9807852804f,  0.9238795325f,  0.8314696123f,
   0.7071067812f,  0.5555702330f,  0.3826834324f,  0.1950903220f,
   0.0000000000f, -0.1950903220f, -0.3826834324f, -0.5555702330f,
  -0.7071067812f, -0.8314696123f, -0.9238795325f, -0.9807852804f,
  -1.0000000000f, -0.9807852804f, -0.9238795325f, -0.8314696123f,
  -0.7071067812f, -0.5555702330f, -0.3826834324f, -0.1950903220f
};

} // namespace

__device__ __forceinline__ ushort f2bf(float f) {
    union { float f; unsigned u; } v; v.f = f;
    const unsigned r = (v.u + 0x7FFFu + ((v.u >> 16) & 1u)) >> 16;
    return (ushort)r;
}
// pack two f32 -> (bf16 lo, bf16 hi) u32 — pure C (proven; NO inline asm)
__device__ __forceinline__ uint pk(float lo, float hi) {
    return (uint)f2bf(lo) | ((uint)f2bf(hi) << 16);
}
__device__ __forceinline__ bf16x8 neg8(bf16x8 a) {
    union { bf16x8 v; uint4 u; } t; t.v = a;
    t.u.x ^= 0x80008000u; t.u.y ^= 0x80008000u;
    t.u.z ^= 0x80008000u; t.u.w ^= 0x80008000u;
    return t.v;
}

// ---------------------------------------------------------------------------
// Pre-pack (unchanged from r7).
// ---------------------------------------------------------------------------
__global__ __launch_bounds__(256) void k_pack(const float* __restrict__ w1,
                                              const float* __restrict__ w2,
                                              ushort* __restrict__ pw) {
    const unsigned idx = blockIdx.x * 256u + threadIdx.x;
    if (idx < W_ELEMS) {
        const unsigned mi = idx / 36864u;       // mat*4 + blk
        const unsigned r  = idx % 36864u;
        const unsigned kk = r / 6144u;
        const unsigned r2 = r % 6144u;
        const unsigned nf = r2 / 512u;
        const unsigned r3 = r2 % 512u;
        const unsigned lane = r3 / 8u;
        const unsigned i  = r3 % 8u;
        const unsigned d   = kk * 32u + (lane >> 4) * 8u + i;
        const unsigned col = nf * 16u + (lane & 15u);
        const unsigned mat = mi >> 2, blk = mi & 3u;
        const float* src;
        if      (mat == 0u) src = w1 + (size_t)(0 * 4 + blk) * BLK * BLK;
        else if (mat == 1u) src = w1 + (size_t)(1 * 4 + blk) * BLK * BLK;
        else if (mat == 2u) src = w2 + (size_t)(0 * 4 + blk) * BLK * BLK;
        else                src = w2 + (size_t)(1 * 4 + blk) * BLK * BLK;
        pw[idx] = f2bf(src[(size_t)d * BLK + col]);
    } else if (idx < PW_ELEMS) {
        const unsigned t = idx - (unsigned)W_ELEMS;   // 0..8191
        const unsigned mat = t >> 10;
        const unsigned rr  = t & 1023u;
        const unsigned mf  = rr >> 9;
        const unsigned q   = rr & 511u;
        const unsigned lane = q >> 3, i = q & 7u;
        const unsigned row = mf * 16u + (lane & 15u);   // output idx (kh / w)
        const unsigned col = (lane >> 4) * 8u + i;      // reduce idx (h / kw)
        const unsigned ang = (row * col) & 31u;
        float v;
        if      (mat == 0u) v = C32[ang] * 0.03125f;
        else if (mat == 1u) v = S32[ang] * 0.03125f;
        else if (mat == 2u) v = -S32[ang] * 0.03125f;
        else if (mat == 3u) v = C32[ang];
        else if (mat == 4u) v = S32[ang];
        else if (mat == 5u) v = -S32[ang];
        else if (mat == 6u) {
            if      (col == 0u)  v = 0.03125f;
            else if (col < 16u)  v = 2.f * C32[ang] * 0.03125f;
            else if (col == 16u) v = C32[(16u * row) & 31u] * 0.03125f;
            else                 v = 0.f;
        } else {
            v = (col >= 1u && col <= 15u) ? (-2.f * S32[ang] * 0.03125f) : 0.f;
        }
        pw[idx] = f2bf(v);
    }
}

// ---------------------------------------------------------------------------
// k1: W-FFT as MFMA (unchanged from r7).
// ---------------------------------------------------------------------------
__global__ __launch_bounds__(256) void k_rfft_w(const float* __restrict__ x,
                                                ushort* __restrict__ spec,
                                                const ushort* __restrict__ pw) {
    __shared__ uint xb[16 * 384];

    const int bid = blockIdx.x;
    const int cq = bid & 3;
    const int hp = (bid >> 2) & 15;
    const int b  = bid >> 6;
    const int tid = threadIdx.x;
    const int wv = tid >> 6, l = tid & 63, lc = l & 15, lg = l >> 4;

#pragma unroll
    for (int it = 0; it < 6; ++it) {
        const int flat = it * 256 + tid;        // 0..1535
        const int h  = flat / 768;
        const int rm = flat % 768;
        const int wp = rm / 48;
        const int c4 = rm % 48;
        const float* p = x + ((size_t)(b * 1024 + (hp * 2 + h) * 32 + wp * 2) * CC)
                           + cq * 192 + c4 * 4;
        const float4 a  = *(const float4*)p;
        const float4 bb = *(const float4*)(p + CC);
        uint4 u;
        u.x = pk(a.x, bb.x); u.y = pk(a.y, bb.y);
        u.z = pk(a.z, bb.z); u.w = pk(a.w, bb.w);
        const int col = (h * 192 + c4 * 4) ^ (((wp >> 2) & 3) << 3);
        *(uint4*)&xb[wp * 384 + col] = u;
    }
    __syncthreads();

    const ushort* TW = pw + W_ELEMS;
    bf16x8 ac[2], as[2];
#pragma unroll
    for (int m = 0; m < 2; ++m) {
        ac[m] = *(const bf16x8*)(TW + ((size_t)(3 * 2 + m) * 64 + l) * 8);  // C
        as[m] = *(const bf16x8*)(TW + ((size_t)(5 * 2 + m) * 64 + l) * 8);  // -S
    }

    f32x4 aR[2][6] = {}, aI[2][6] = {};
#pragma unroll
    for (int j = 0; j < 6; ++j) {
        const int nf = (j < 3) ? (wv * 3 + j) : (12 + wv * 3 + (j - 3));
        union { bf16x8 v; uint d[4]; } u;
#pragma unroll
        for (int t = 0; t < 4; ++t) {
            const int wp = lg * 4 + t;
            u.d[t] = xb[wp * 384 + ((nf * 16 + lc) ^ (lg << 3))];
        }
#pragma unroll
        for (int m = 0; m < 2; ++m) {
            aR[m][j] = __builtin_amdgcn_mfma_f32_16x16x32_bf16(ac[m], u.v, aR[m][j], 0, 0, 0);
            aI[m][j] = __builtin_amdgcn_mfma_f32_16x16x32_bf16(as[m], u.v, aI[m][j], 0, 0, 0);
        }
    }

    uint* spec32 = (uint*)spec;
    const int swz = (hp & 7) << 1;
#pragma unroll
    for (int m = 0; m < 2; ++m)
#pragma unroll
        for (int j = 0; j < 3; ++j)
#pragma unroll
            for (int r = 0; r < 4; ++r) {
                if (m == 1 && (lg != 0 || r != 0)) continue;   // keep kw==16 only
                const int kw = m * 16 + lg * 4 + r;
                const int csub = cq * 12 + wv * 3 + j;
                const size_t pos = ((size_t)(b * WF + kw) * 2) * 12288
                                 + csub * 256 + hp * 16 + (lc ^ swz);
                spec32[pos]         = pk(aR[m][j][r], aR[m][j + 3][r]);
                spec32[pos + 12288] = pk(aI[m][j][r], aI[m][j + 3][r]);
            }
}

// ---------------------------------------------------------------------------
// k2: fused fftH + S1 + S2 + S3 + ifftH, TWO tiles per WG (b-pair, same kw,
// same blk -> same weights). Per tile, 3 LDS regions (12 csub x 528 ushorts):
//  R0: Xilv -> Ysub(r) -> r1sub -> r2sub
//  R1: Xilv(i) -> Ysub(i) -> i1sub -> i2_t(ilv)
//  R2: r2_t(ilv)
// Weight fragments loaded ONCE per kk, applied to both tiles.
// 7 barriers total (3.5 per tile).  Dynamic LDS 76032 B -> 2 WG/CU.
// ---------------------------------------------------------------------------
__global__ __launch_bounds__(256, 2) void k_fft_mix(
        ushort* __restrict__ spec,
        const ushort* __restrict__ pw,
        const float* __restrict__ b1, const float* __restrict__ b2) {

    extern __shared__ ushort ldsraw[];
    typedef ushort Regions[3][6336];
    Regions* lds = (Regions*)ldsraw;     // lds[t][r][pos]

    const int bid = blockIdx.x;
    const int blk = bid / (32 * WF);
    const int rem = bid % (32 * WF);
    const int bp  = rem / WF;            // b-pair 0..31
    const int kw  = rem % WF;
    const int tid = threadIdx.x;
    const int wv = tid >> 6, l = tid & 63, lc = l & 15, lg = l >> 4;

    size_t gRt[2];
    gRt[0] = ((size_t)((bp * 2) * WF + kw) * 2) * PLANE_U + blk * 6144;
    gRt[1] = gRt[0] + (size_t)WF * 2 * PLANE_U;

#pragma unroll
    for (int j = 0; j < 3; ++j) {
        const int q = tid + 256 * j;
        const int dst = (q >> 6) * 528 + (q & 63) * 8;
#pragma unroll
        for (int t = 0; t < 2; ++t) {
            *(uint4*)&lds[t][0][dst] = *(const uint4*)(spec + gRt[t] + q * 8);
            *(uint4*)&lds[t][1][dst] = *(const uint4*)(spec + gRt[t] + PLANE_U + q * 8);
        }
    }
    __syncthreads();                                   // A

    const ushort* TW = pw + W_ELEMS;
    const int col0 = wv * 48;

    // ================= P1: forward H-FFT (in-place own stripes) ====
    {
        bf16x8 cf[2], sf[2], sfn[2];
#pragma unroll
        for (int m = 0; m < 2; ++m) {
            cf[m]  = *(const bf16x8*)(TW + ((size_t)(0 * 2 + m) * 64 + l) * 8);
            sf[m]  = *(const bf16x8*)(TW + ((size_t)(1 * 2 + m) * 64 + l) * 8);
            sfn[m] = *(const bf16x8*)(TW + ((size_t)(2 * 2 + m) * 64 + l) * 8);
        }
#pragma unroll
        for (int t = 0; t < 2; ++t) {
            bf16x8 xr[3], xi[3];
#pragma unroll
            for (int n = 0; n < 3; ++n) {
                const int csub = wv * 3 + n;
                union { bf16x8 v; uint d[4]; } ur, ui;
#pragma unroll
                for (int tt = 0; tt < 4; ++tt) {
                    const int hp = lg * 4 + tt;
                    const int pos = csub * 528 + hp * 32 + ((lc ^ ((hp & 7) << 1)) << 1);
                    ur.d[tt] = *(const uint*)&lds[t][0][pos];
                    ui.d[tt] = *(const uint*)&lds[t][1][pos];
                }
                xr[n] = ur.v; xi[n] = ui.v;
            }
            f32x4 yr[2][3] = {}, yi[2][3] = {};
#pragma unroll
            for (int m = 0; m < 2; ++m)
#pragma unroll
                for (int n = 0; n < 3; ++n) {
                    yr[m][n] = __builtin_amdgcn_mfma_f32_16x16x32_bf16(cf[m],  xr[n], yr[m][n], 0, 0, 0);
                    yr[m][n] = __builtin_amdgcn_mfma_f32_16x16x32_bf16(sf[m],  xi[n], yr[m][n], 0, 0, 0);
                    yi[m][n] = __builtin_amdgcn_mfma_f32_16x16x32_bf16(cf[m],  xi[n], yi[m][n], 0, 0, 0);
                    yi[m][n] = __builtin_amdgcn_mfma_f32_16x16x32_bf16(sfn[m], xr[n], yi[m][n], 0, 0, 0);
                }
#pragma unroll
            for (int m = 0; m < 2; ++m)
#pragma unroll
                for (int n = 0; n < 3; ++n)
#pragma unroll
                    for (int rp = 0; rp < 2; ++rp) {
                        const uint ur = pk(yr[m][n][2 * rp], yr[m][n][2 * rp + 1]);
                        const uint ui = pk(yi[m][n][2 * rp], yi[m][n][2 * rp + 1]);
                        const int p0 = (wv * 3 + n) * 528 + (m * 16 + lg * 4 + 2 * rp) * 16 + lc;
                        lds[t][0][p0] = (ushort)ur; lds[t][0][p0 + 16] = (ushort)(ur >> 16);
                        lds[t][1][p0] = (ushort)ui; lds[t][1][p0 + 16] = (ushort)(ui >> 16);
                    }
        }
    }
    __syncthreads();                                   // B

    const ushort* pW1r = pw + (size_t)(0 * 4 + blk) * 36864;
    const ushort* pW1i = pw + (size_t)(1 * 4 + blk) * 36864;
    const ushort* pW2r = pw + (size_t)(2 * 4 + blk) * 36864;
    const ushort* pW2i = pw + (size_t)(3 * 4 + blk) * 36864;

    // ================= P2: layer 1 + relu (weights shared across tiles) ====
    {
        f32x4 aR[2][2][3], aI[2][2][3];       // [tile][m][n]
#pragma unroll
        for (int n = 0; n < 3; ++n) {
            const float br = b1[(size_t)(0 * 4 + blk) * BLK + col0 + n * 16 + lc];
            const float bi = b1[(size_t)(1 * 4 + blk) * BLK + col0 + n * 16 + lc];
#pragma unroll
            for (int t = 0; t < 2; ++t)
#pragma unroll
                for (int m = 0; m < 2; ++m) {
                    aR[t][m][n] = (f32x4){br, br, br, br};
                    aI[t][m][n] = (f32x4){bi, bi, bi, bi};
                }
        }
#pragma unroll
        for (int kk = 0; kk < 6; ++kk) {
            const int csubA = 2 * kk + (lg >> 1);
            const int apos  = csubA * 528 + lc * 16 + (lg & 1) * 8;
            bf16x8 wr[3], wi[3];
#pragma unroll
            for (int n = 0; n < 3; ++n) {
                const size_t off = ((size_t)(kk * 12 + wv * 3 + n) * 64 + l) * 8;
                wr[n] = *(const bf16x8*)(pW1r + off);
                wi[n] = *(const bf16x8*)(pW1i + off);
            }
#pragma unroll
            for (int t = 0; t < 2; ++t) {
                bf16x8 ar[2], ai[2], ain[2];
#pragma unroll
                for (int m = 0; m < 2; ++m) {
                    ar[m]  = *(const bf16x8*)&lds[t][0][apos + m * 256];
                    ai[m]  = *(const bf16x8*)&lds[t][1][apos + m * 256];
                    ain[m] = neg8(ai[m]);
                }
#pragma unroll
                for (int m = 0; m < 2; ++m)
#pragma unroll
                    for (int n = 0; n < 3; ++n) {
                        aR[t][m][n] = __builtin_amdgcn_mfma_f32_16x16x32_bf16(ar[m],  wr[n], aR[t][m][n], 0, 0, 0);
                        aR[t][m][n] = __builtin_amdgcn_mfma_f32_16x16x32_bf16(ain[m], wi[n], aR[t][m][n], 0, 0, 0);
                        aI[t][m][n] = __builtin_amdgcn_mfma_f32_16x16x32_bf16(ar[m],  wi[n], aI[t][m][n], 0, 0, 0);
                        aI[t][m][n] = __builtin_amdgcn_mfma_f32_16x16x32_bf16(ai[m],  wr[n], aI[t][m][n], 0, 0, 0);
                    }
            }
        }
        __syncthreads();                               // C (all Y reads done)
#pragma unroll
        for (int t = 0; t < 2; ++t)
#pragma unroll
            for (int m = 0; m < 2; ++m)
#pragma unroll
                for (int n = 0; n < 3; ++n)
#pragma unroll
                    for (int rp = 0; rp < 2; ++rp) {
                        const uint ur = pk(fmaxf(aR[t][m][n][2 * rp], 0.f), fmaxf(aR[t][m][n][2 * rp + 1], 0.f));
                        const uint ui = pk(fmaxf(aI[t][m][n][2 * rp], 0.f), fmaxf(aI[t][m][n][2 * rp + 1], 0.f));
                        const int p0 = (wv * 3 + n) * 528 + (m * 16 + lg * 4 + 2 * rp) * 16 + lc;
                        lds[t][0][p0] = (ushort)ur; lds[t][0][p0 + 16] = (ushort)(ur >> 16);
                        lds[t][1][p0] = (ushort)ui; lds[t][1][p0 + 16] = (ushort)(ui >> 16);
                    }
    }
    __syncthreads();                                   // D

    // ================= P3: r2 = r1 W2r - i1 W2i + b2r =================
    {
        f32x4 cR[2][2][3];
#pragma unroll
        for (int n = 0; n < 3; ++n) {
            const float br = b2[(size_t)(0 * 4 + blk) * BLK + col0 + n * 16 + lc];
#pragma unroll
            for (int t = 0; t < 2; ++t)
#pragma unroll
                for (int m = 0; m < 2; ++m) cR[t][m][n] = (f32x4){br, br, br, br};
        }
#pragma unroll
        for (int kk = 0; kk < 6; ++kk) {
            const int csubA = 2 * kk + (lg >> 1);
            const int apos  = csubA * 528 + lc * 16 + (lg & 1) * 8;
            bf16x8 wr[3], wi[3];
#pragma unroll
            for (int n = 0; n < 3; ++n) {
                const size_t off = ((size_t)(kk * 12 + wv * 3 + n) * 64 + l) * 8;
                wr[n] = *(const bf16x8*)(pW2r + off);
                wi[n] = *(const bf16x8*)(pW2i + off);
            }
#pragma unroll
            for (int t = 0; t < 2; ++t) {
                bf16x8 ar[2], ain[2];
#pragma unroll
                for (int m = 0; m < 2; ++m) {
                    ar[m]  = *(const bf16x8*)&lds[t][0][apos + m * 256];
                    ain[m] = neg8(*(const bf16x8*)&lds[t][1][apos + m * 256]);
                }
#pragma unroll
                for (int m = 0; m < 2; ++m)
#pragma unroll
                    for (int n = 0; n < 3; ++n) {
                        cR[t][m][n] = __builtin_amdgcn_mfma_f32_16x16x32_bf16(ar[m],  wr[n], cR[t][m][n], 0, 0, 0);
                        cR[t][m][n] = __builtin_amdgcn_mfma_f32_16x16x32_bf16(ain[m], wi[n], cR[t][m][n], 0, 0, 0);
                    }
            }
        }
        __syncthreads();                               // E (all r1/i1 reads done)
#pragma unroll
        for (int t = 0; t < 2; ++t)
#pragma unroll
            for (int m = 0; m < 2; ++m)
#pragma unroll
                for (int n = 0; n < 3; ++n) {
                    const int csub = wv * 3 + n;
#pragma unroll
                    for (int rp = 0; rp < 2; ++rp) {
                        const uint p = pk(cR[t][m][n][2 * rp], cR[t][m][n][2 * rp + 1]);
                        const int kh0 = m * 16 + lg * 4 + 2 * rp;
                        lds[t][0][csub * 528 + kh0 * 16 + lc]       = (ushort)p;
                        lds[t][0][csub * 528 + (kh0 + 1) * 16 + lc] = (ushort)(p >> 16);
                        const int hp = kh0 >> 1;
                        const int post = csub * 528 + hp * 32 + ((lc ^ ((hp & 7) << 1)) << 1);
                        *(uint*)&lds[t][2][post] = p;
                    }
                }
    }
    __syncthreads();                                   // F

    // ================= P4: i2 = r2 W2i + i1 W2r + b2i =================
    {
        f32x4 cI[2][2][3];
#pragma unroll
        for (int n = 0; n < 3; ++n) {
            const float bi = b2[(size_t)(1 * 4 + blk) * BLK + col0 + n * 16 + lc];
#pragma unroll
            for (int t = 0; t < 2; ++t)
#pragma unroll
                for (int m = 0; m < 2; ++m) cI[t][m][n] = (f32x4){bi, bi, bi, bi};
        }
#pragma unroll
        for (int kk = 0; kk < 6; ++kk) {
            const int csubA = 2 * kk + (lg >> 1);
            const int apos  = csubA * 528 + lc * 16 + (lg & 1) * 8;
            bf16x8 wi[3], wr[3];
#pragma unroll
            for (int n = 0; n < 3; ++n) {
                const size_t off = ((size_t)(kk * 12 + wv * 3 + n) * 64 + l) * 8;
                wi[n] = *(const bf16x8*)(pW2i + off);
                wr[n] = *(const bf16x8*)(pW2r + off);
            }
#pragma unroll
            for (int t = 0; t < 2; ++t) {
                bf16x8 a2[2], i1[2];
#pragma unroll
                for (int m = 0; m < 2; ++m) {
                    a2[m] = *(const bf16x8*)&lds[t][0][apos + m * 256];   // r2
                    i1[m] = *(const bf16x8*)&lds[t][1][apos + m * 256];   // i1
                }
#pragma unroll
                for (int m = 0; m < 2; ++m)
#pragma unroll
                    for (int n = 0; n < 3; ++n) {
                        cI[t][m][n] = __builtin_amdgcn_mfma_f32_16x16x32_bf16(a2[m], wi[n], cI[t][m][n], 0, 0, 0);
                        cI[t][m][n] = __builtin_amdgcn_mfma_f32_16x16x32_bf16(i1[m], wr[n], cI[t][m][n], 0, 0, 0);
                    }
            }
        }
        __syncthreads();                               // G (all i1 reads done)
#pragma unroll
        for (int t = 0; t < 2; ++t)
#pragma unroll
            for (int m = 0; m < 2; ++m)
#pragma unroll
                for (int n = 0; n < 3; ++n) {
                    const int csub = wv * 3 + n;
#pragma unroll
                    for (int rp = 0; rp < 2; ++rp) {
                        const int hp = (m * 16 + lg * 4 + 2 * rp) >> 1;
                        const int post = csub * 528 + hp * 32 + ((lc ^ ((hp & 7) << 1)) << 1);
                        *(uint*)&lds[t][1][post] = pk(cI[t][m][n][2 * rp], cI[t][m][n][2 * rp + 1]);
                    }
                }
    }
    // no barrier: P5 reads only this wave's own stripes

    // ================= P5: inverse H-FFT + store =================
    {
        bf16x8 ci[2], si[2], sn[2];
#pragma unroll
        for (int m = 0; m < 2; ++m) {
            ci[m] = *(const bf16x8*)(TW + ((size_t)(3 * 2 + m) * 64 + l) * 8);
            si[m] = *(const bf16x8*)(TW + ((size_t)(4 * 2 + m) * 64 + l) * 8);
            sn[m] = *(const bf16x8*)(TW + ((size_t)(5 * 2 + m) * 64 + l) * 8);
        }
#pragma unroll
        for (int t = 0; t < 2; ++t) {
            bf16x8 r2b[3], i2b[3];
#pragma unroll
            for (int n = 0; n < 3; ++n) {
                const int csub = wv * 3 + n;
                union { bf16x8 v; uint d[4]; } ur, ui;
#pragma unroll
                for (int tt = 0; tt < 4; ++tt) {
                    const int hp = lg * 4 + tt;
                    const int pos = csub * 528 + hp * 32 + ((lc ^ ((hp & 7) << 1)) << 1);
                    ur.d[tt] = *(const uint*)&lds[t][2][pos];
                    ui.d[tt] = *(const uint*)&lds[t][1][pos];
                }
                r2b[n] = ur.v; i2b[n] = ui.v;
            }
            f32x4 zr[2][3] = {}, zi[2][3] = {};
#pragma unroll
            for (int m = 0; m < 2; ++m)
#pragma unroll
                for (int n = 0; n < 3; ++n) {
                    zr[m][n] = __builtin_amdgcn_mfma_f32_16x16x32_bf16(ci[m], r2b[n], zr[m][n], 0, 0, 0);
                    zr[m][n] = __builtin_amdgcn_mfma_f32_16x16x32_bf16(sn[m], i2b[n], zr[m][n], 0, 0, 0);
                    zi[m][n] = __builtin_amdgcn_mfma_f32_16x16x32_bf16(ci[m], i2b[n], zi[m][n], 0, 0, 0);
                    zi[m][n] = __builtin_amdgcn_mfma_f32_16x16x32_bf16(si[m], r2b[n], zi[m][n], 0, 0, 0);
                }
#pragma unroll
            for (int m = 0; m < 2; ++m)
#pragma unroll
                for (int n = 0; n < 3; ++n) {
                    const size_t cbase = gRt[t] + (size_t)(wv * 3 + n) * 512;
#pragma unroll
                    for (int rp = 0; rp < 2; ++rp) {
                        const int hp = (m * 16 + lg * 4 + 2 * rp) >> 1;
                        const size_t pos = cbase + hp * 32 + ((lc ^ ((hp & 7) << 1)) << 1);
                        *(uint*)(spec + pos)           = pk(zr[m][n][2 * rp], zr[m][n][2 * rp + 1]);
                        *(uint*)(spec + pos + PLANE_U) = pk(zi[m][n][2 * rp], zi[m][n][2 * rp + 1]);
                    }
                }
        }
    }
}

// ---------------------------------------------------------------------------
// k3: W-irfft as MFMA (unchanged from r7).
// ---------------------------------------------------------------------------
__global__ __launch_bounds__(256) void k_irfft_w(const ushort* __restrict__ spec,
                                                 float* __restrict__ out,
                                                 const ushort* __restrict__ pw) {
    __shared__ uint rawR[17 * 198];
    __shared__ uint rawI[17 * 198];

    const int bid = blockIdx.x;
    const int cq = bid & 3;
    const int hp = (bid >> 2) & 15;
    const int b  = bid >> 6;
    const int tid = threadIdx.x;
    const int wv = tid >> 6, l = tid & 63, lc = l & 15, lg = l >> 4;

    const uint* spec32 = (const uint*)spec;

#pragma unroll
    for (int it = 0; it < 13; ++it) {
        const int slot = it * 256 + tid;
        if (slot < 3264) {
            const int part = slot & 7;            // 8B unit within chunk
            const int c2   = slot >> 3;           // 0..407
            const int plane = c2 / 204;
            const int q  = c2 % 204;
            const int kw = q / 12, csub = q % 12;
            const size_t gpos = ((size_t)(b * WF + kw) * 2 + plane) * 12288
                              + (cq * 12 + csub) * 256 + hp * 16 + part * 2;
            const uint2 v = *(const uint2*)(spec32 + gpos);
            uint* dst = plane ? rawI : rawR;
            *(uint2*)&dst[kw * 198 + csub * 16 + part * 2] = v;
        }
    }
    __syncthreads();

    const ushort* TW = pw + W_ELEMS;
    bf16x8 twA[2], twB[2];
#pragma unroll
    for (int m = 0; m < 2; ++m) {
        twA[m] = *(const bf16x8*)(TW + ((size_t)(6 * 2 + m) * 64 + l) * 8);
        twB[m] = *(const bf16x8*)(TW + ((size_t)(7 * 2 + m) * 64 + l) * 8);
    }

    int rowoff[8];
#pragma unroll
    for (int i = 0; i < 8; ++i) {
        int kwv = lg * 8 + i;
        if (kwv > 16) kwv = 16;        // clamped reads; A/B cols >16 are zero
        rowoff[i] = kwv * 396;         // ushort units
    }

    const ushort* rr = (const ushort*)rawR;
    const ushort* ri = (const ushort*)rawI;
    const int swz = (hp & 7) << 1;

    f32x4 acc[2][6] = {};
#pragma unroll
    for (int j = 0; j < 6; ++j) {
        const int coll = (wv * 6 + j) * 16 + lc;     // 0..383
        const int h  = coll & 1;
        const int cL = coll >> 1;
        const int bu = ((cL >> 4) * 16 + ((cL & 15) ^ swz)) * 2 + h;
        union { bf16x8 v; ushort s[8]; } fr, fi;
#pragma unroll
        for (int i = 0; i < 8; ++i) {
            fr.s[i] = rr[rowoff[i] + bu];
            fi.s[i] = ri[rowoff[i] + bu];
        }
#pragma unroll
        for (int m = 0; m < 2; ++m) {
            acc[m][j] = __builtin_amdgcn_mfma_f32_16x16x32_bf16(twA[m], fr.v, acc[m][j], 0, 0, 0);
            acc[m][j] = __builtin_amdgcn_mfma_f32_16x16x32_bf16(twB[m], fi.v, acc[m][j], 0, 0, 0);
        }
    }

#pragma unroll
    for (int m = 0; m < 2; ++m)
#pragma unroll
        for (int j = 0; j < 6; ++j) {
            const int coll = (wv * 6 + j) * 16 + lc;
            const int h  = coll & 1;
            const int c  = cq * 192 + (coll >> 1);
#pragma unroll
            for (int r = 0; r < 4; ++r) {
                const int w = m * 16 + lg * 4 + r;
                out[((size_t)(b * 1024 + (hp * 2 + h) * 32 + w)) * CC + c] = acc[m][j][r];
            }
        }
}

// ---------------------------------------------------------------------------
extern "C" void kernel_launch(void* const* d_in, const int* in_sizes, int n_in,
                              void* d_out, int out_size, void* d_ws, size_t ws_size,
                              hipStream_t stream) {
    const float* x  = (const float*)d_in[0];
    const float* w1 = (const float*)d_in[1];
    const float* b1 = (const float*)d_in[2];
    const float* w2 = (const float*)d_in[3];
    const float* b2 = (const float*)d_in[4];
    float* out = (float*)d_out;

    ushort* pw   = (ushort*)d_ws;
    ushort* spec = pw + PW_ELEMS;

    constexpr unsigned K2_LDS = 2u * 3u * 6336u * 2u;   // 76032 B

    // raise dynamic-LDS cap for k2 (host-side attribute set; graph-capture safe,
    // deterministic, idempotent)
    (void)hipFuncSetAttribute((const void*)k_fft_mix,
                              hipFuncAttributeMaxDynamicSharedMemorySize,
                              (int)K2_LDS);

    k_pack<<<dim3((unsigned)(PW_ELEMS / 256)), dim3(256), 0, stream>>>(w1, w2, pw);
    k_rfft_w<<<dim3(BATCH * 16 * 4), dim3(256), 0, stream>>>(x, spec, pw);
    k_fft_mix<<<dim3(4 * 32 * WF), dim3(256), K2_LDS, stream>>>(spec, pw, b1, b2);
    k_irfft_w<<<dim3(BATCH * 16 * 4), dim3(256), 0, stream>>>(spec, out, pw);
}